// Round 4
// baseline (246.444 us; speedup 1.0000x reference)
//
#include <hip/hip_runtime.h>
#include <math.h>

#define EPS 1e-12f
constexpr int N_ROWS = 262144;
constexpr int KCODES = 1024;
constexpr int DIM    = 64;
constexpr int CAP    = 65536;     // recheck list capacity
constexpr int CHUNK_SH = 8192;    // ushorts per 64-code chunk (hi+lo)

typedef __attribute__((ext_vector_type(8)))  short  short8;
typedef __attribute__((ext_vector_type(16))) float  float16;

__device__ inline unsigned short f2bf(float f) {
    unsigned int u = __float_as_uint(f);
    u = u + 0x7fff + ((u >> 16) & 1);           // RNE
    return (unsigned short)(u >> 16);
}
__device__ inline float bf2f(unsigned short s) {
    return __uint_as_float(((unsigned int)s) << 16);
}

// ---------- K1: normalize codebook -> cc, cnT (transposed), bf16 hi/lo frags ----------
// 64-code chunks: chunk c holds codes [c*64, c*64+64).
// Frag layout (B-operand, 32x32x16): lane l holds B[k=16s+8*(l>>5)+j][n=32*t+(l&31)]
// ushort idx = c*8192 + ((t*4+s)*2+p)*512 + lane*8 + j   (p: 0=hi,1=lo)
__global__ __launch_bounds__(256)
void vq_prep(const float* __restrict__ cb, float* __restrict__ cnT,
             float* __restrict__ cc, unsigned short* __restrict__ frag,
             int* __restrict__ cnt, float* __restrict__ dloss) {
    int n = blockIdx.x * 4 + (threadIdx.x >> 6);   // code
    int d = threadIdx.x & 63;                      // dim
    float v = cb[n * DIM + d];
    float s = v * v;
    #pragma unroll
    for (int off = 32; off; off >>= 1) s += __shfl_xor(s, off, 64);
    float vn = v / fmaxf(sqrtf(s), EPS);
    cnT[d * KCODES + n] = vn;                      // transposed for recheck
    float s2 = vn * vn;
    #pragma unroll
    for (int off = 32; off; off >>= 1) s2 += __shfl_xor(s2, off, 64);
    if (d == 0) cc[n] = s2;
    unsigned short hi = f2bf(vn);
    unsigned short lo = f2bf(vn - bf2f(hi));
    int c = n >> 6, t = (n >> 5) & 1;
    int lane = (n & 31) + 32 * ((d >> 3) & 1);
    int si = d >> 4, j = d & 7;
    size_t base = (size_t)c * CHUNK_SH + (size_t)((t * 4 + si) * 2) * 512 + lane * 8 + j;
    frag[base]       = hi;
    frag[base + 512] = lo;
    if (n == 0 && d == 0) { *cnt = 0; *dloss = 0.f; }
}

// ---------- K2: MFMA distances, packed-key argmin, fused gather/out_q/loss ----------
__global__ __launch_bounds__(256, 4)
void vq_mfma(const float* __restrict__ x, const unsigned short* __restrict__ frag,
             const float* __restrict__ cb, float* __restrict__ out_q,
             float* __restrict__ out_idx, int* __restrict__ cnt,
             int* __restrict__ list, float* __restrict__ partial) {
    __shared__ unsigned short Blds[2][CHUNK_SH];   // 2 x 16 KB double buffer
    __shared__ int   ridx[128];
    __shared__ float redl[4];

    const int tid = threadIdx.x;
    const int w = tid >> 6, l = tid & 63;
    const int lc = l & 31, h = l >> 5;
    const int row0 = blockIdx.x * 128;
    const int row  = row0 + w * 32 + lc;           // A-operand row for this lane

    // --- A: 32 floats/lane (one row half per h), norm via shfl, bf16 hi/lo split ---
    short8 ahi[4], alo[4];
    {
        float xv[4][8]; float ss = 0.f;
        #pragma unroll
        for (int s = 0; s < 4; ++s) {
            const float* p = x + (size_t)row * DIM + s * 16 + h * 8;
            float4 a = *(const float4*)p;
            float4 b = *(const float4*)(p + 4);
            xv[s][0]=a.x; xv[s][1]=a.y; xv[s][2]=a.z; xv[s][3]=a.w;
            xv[s][4]=b.x; xv[s][5]=b.y; xv[s][6]=b.z; xv[s][7]=b.w;
            ss += a.x*a.x + a.y*a.y + a.z*a.z + a.w*a.w
                + b.x*b.x + b.y*b.y + b.z*b.z + b.w*b.w;
        }
        ss += __shfl_xor(ss, 32, 64);
        float inv = 1.0f / fmaxf(sqrtf(ss), EPS);
        #pragma unroll
        for (int s = 0; s < 4; ++s)
            #pragma unroll
            for (int j = 0; j < 8; ++j) {
                float v = xv[s][j] * inv;
                unsigned short hb = f2bf(v);
                unsigned short lb = f2bf(v - bf2f(hb));
                ahi[s][j] = (short)hb;
                alo[s][j] = (short)lb;
            }
    }

    int m1[16], m2[16];
    #pragma unroll
    for (int r = 0; r < 16; ++r) { m1[r] = 0; m2[r] = 0; }

    // stage chunk 0: per thread 4 x 16 B, lane-linear
    {
        const unsigned short* g = frag + tid * 8;
        #pragma unroll
        for (int q = 0; q < 4; ++q)
            __builtin_amdgcn_global_load_lds(
                (const __attribute__((address_space(1))) unsigned int*)(g + q * 2048),
                (__attribute__((address_space(3))) unsigned int*)&Blds[0][(tid + 256 * q) * 8],
                16, 0, 0);
    }

    for (int c = 0; c < 16; ++c) {
        __syncthreads();
        if (c < 15) {      // prefetch next chunk into the other buffer
            const unsigned short* g = frag + (size_t)(c + 1) * CHUNK_SH + tid * 8;
            #pragma unroll
            for (int q = 0; q < 4; ++q)
                __builtin_amdgcn_global_load_lds(
                    (const __attribute__((address_space(1))) unsigned int*)(g + q * 2048),
                    (__attribute__((address_space(3))) unsigned int*)&Blds[(c + 1) & 1][(tid + 256 * q) * 8],
                    16, 0, 0);
        }
        const unsigned short* B = Blds[c & 1];
        #pragma unroll
        for (int t = 0; t < 2; ++t) {
            float16 acc;
            #pragma unroll
            for (int r = 0; r < 16; ++r) acc[r] = 2.0f;   // bias: acc = 2 + dot > 0
            #pragma unroll
            for (int s = 0; s < 4; ++s) {
                short8 bhi = *((const short8*)&B[((t * 4 + s) * 2    ) * 512] + l);
                short8 blo = *((const short8*)&B[((t * 4 + s) * 2 + 1) * 512] + l);
                acc = __builtin_amdgcn_mfma_f32_32x32x16_bf16(ahi[s], bhi, acc, 0, 0, 0);
                acc = __builtin_amdgcn_mfma_f32_32x32x16_bf16(alo[s], bhi, acc, 0, 0, 0);
                acc = __builtin_amdgcn_mfma_f32_32x32x16_bf16(ahi[s], blo, acc, 0, 0, 0);
            }
            int vcode = (1023 - c * 64 - t * 32) - lc;    // tie-break: max key -> lowest code
            #pragma unroll
            for (int r = 0; r < 16; ++r) {
                int k = (__float_as_int(acc[r]) & (int)0xFFFFFC00) | vcode;
                int t0 = min(m1[r], k);
                m1[r] = max(m1[r], k);
                m2[r] = max(m2[r], t0);
            }
        }
    }

    // --- cross-lane top-2 merge over the 32 code-lanes ---
    int flags = 0;
    #pragma unroll
    for (int r = 0; r < 16; ++r) {
        int a = m1[r], b = m2[r];
        #pragma unroll
        for (int off = 1; off < 32; off <<= 1) {
            int oa = __shfl_xor(a, off, 64);
            int ob = __shfl_xor(b, off, 64);
            int nb = max(max(b, ob), min(a, oa));
            a = max(a, oa); b = nb;
        }
        if (lc == 0) {
            int rr = (r & 3) + 8 * (r >> 2) + 4 * h;      // C/D row map (m74/m101)
            ridx[w * 32 + rr] = 1023 - (a & 1023);
            if (((a >> 10) - (b >> 10)) <= 1) flags |= (1 << r);   // near-tie
        }
    }

    // --- one aggregated atomic per flagging wave ---
    {
        int f0 = __shfl(flags, 0, 64), fh = __shfl(flags, 32, 64);
        int tot = __popc(f0) + __popc(fh);
        int base = 0;
        if (l == 0 && tot) base = atomicAdd(cnt, tot);
        base = __shfl(base, 0, 64);
        if (tot && (l == 0 || l == 32)) {
            int off = (l == 32) ? __popc(f0) : 0;
            int fl = flags;
            while (fl) {
                int r = __ffs(fl) - 1; fl &= fl - 1;
                int rr = (r & 3) + 8 * (r >> 2) + 4 * h;
                int p = base + off;
                if (p < CAP) list[p] = row0 + w * 32 + rr;
                ++off;
            }
        }
    }
    __syncthreads();

    if (tid < 128) out_idx[row0 + tid] = (float)ridx[tid];

    // --- gather + out_q + loss partial (x re-read is cache-hot) ---
    float lsum = 0.f;
    const float4* cb4 = (const float4*)cb;
    const float4* x4  = (const float4*)x;
    float4*       o4  = (float4*)out_q;
    #pragma unroll
    for (int i = 0; i < 8; ++i) {
        int f = tid + 256 * i;            // 0..2047
        int r = f >> 4, c4 = f & 15;
        float4 q  = cb4[ridx[r] * 16 + c4];
        float4 xr = x4[(size_t)row0 * 16 + f];
        o4[(size_t)row0 * 16 + f] = q;
        float dx = q.x - xr.x, dy = q.y - xr.y, dz = q.z - xr.z, dw = q.w - xr.w;
        lsum += dx * dx + dy * dy + dz * dz + dw * dw;
    }
    #pragma unroll
    for (int off = 32; off; off >>= 1) lsum += __shfl_xor(lsum, off, 64);
    if (l == 0) redl[w] = lsum;
    __syncthreads();
    if (tid == 0) partial[blockIdx.x] = redl[0] + redl[1] + redl[2] + redl[3];
}

// ---------- K3: exact fp32 recheck of flagged rows + patch idx/out_q/loss ----------
__global__ __launch_bounds__(256)
void vq_recheck(const float* __restrict__ x, const float* __restrict__ cnT,
                const float* __restrict__ cc, const float* __restrict__ cb,
                const int* __restrict__ cnt, const int* __restrict__ list,
                float* __restrict__ out_idx, float* __restrict__ out_q,
                float* __restrict__ dloss) {
    int w = threadIdx.x >> 6, l = threadIdx.x & 63;
    int wid = blockIdx.x * 4 + w, nw = gridDim.x * 4;
    int n = *cnt; if (n > CAP) n = CAP;
    for (int e = wid; e < n; e += nw) {
        int row = list[e];
        float xl = x[(size_t)row * DIM + l];
        float ss = xl * xl;
        #pragma unroll
        for (int off = 32; off; off >>= 1) ss += __shfl_xor(ss, off, 64);
        float inv = 1.0f / fmaxf(sqrtf(ss), EPS);
        float dot[16];
        #pragma unroll
        for (int kk = 0; kk < 16; ++kk) dot[kk] = 0.f;
        for (int d = 0; d < 64; ++d) {
            float xd = __shfl(xl, d, 64);
            #pragma unroll
            for (int kk = 0; kk < 16; ++kk)      // lanes consecutive -> coalesced
                dot[kk] = fmaf(xd, cnT[d * KCODES + l + 64 * kk], dot[kk]);
        }
        float best = INFINITY; int bix = 0x7fffffff;
        #pragma unroll
        for (int kk = 0; kk < 16; ++kk) {
            int k = l + 64 * kk;                 // ascending per lane
            float dist = cc[k] - 2.0f * (inv * dot[kk]);
            if (dist < best) { best = dist; bix = k; }
        }
        #pragma unroll
        for (int off = 1; off < 64; off <<= 1) {
            float ob = __shfl_xor(best, off, 64);
            int   oi = __shfl_xor(bix,  off, 64);
            if (ob < best || (ob == best && oi < bix)) { best = ob; bix = oi; }
        }
        int oldi = (int)out_idx[row];
        if (bix != oldi) {
            float qn = cb[(size_t)bix  * DIM + l];
            float qo = cb[(size_t)oldi * DIM + l];
            float an = qn - xl, ao = qo - xl;
            float dl = an * an - ao * ao;
            #pragma unroll
            for (int off = 32; off; off >>= 1) dl += __shfl_xor(dl, off, 64);
            out_q[(size_t)row * DIM + l] = qn;
            if (l == 0) { out_idx[row] = (float)bix; atomicAdd(dloss, dl); }
        }
    }
}

// ---------- K4: reduce partials (+delta) -> both losses ----------
__global__ __launch_bounds__(256)
void vq_final(const float* __restrict__ partial, const float* __restrict__ dloss,
              float* __restrict__ out_loss) {
    float s = 0.f;
    for (int i = threadIdx.x; i < 2048; i += 256) s += partial[i];
    #pragma unroll
    for (int off = 32; off; off >>= 1) s += __shfl_xor(s, off, 64);
    __shared__ float red[4];
    if ((threadIdx.x & 63) == 0) red[threadIdx.x >> 6] = s;
    __syncthreads();
    if (threadIdx.x == 0) {
        float t = red[0] + red[1] + red[2] + red[3] + *dloss;
        float m = t / (float)((size_t)N_ROWS * DIM);
        out_loss[0] = m;   // codebook_loss
        out_loss[1] = m;   // commitment_loss (same forward value)
    }
}

extern "C" void kernel_launch(void* const* d_in, const int* in_sizes, int n_in,
                              void* d_out, int out_size, void* d_ws, size_t ws_size,
                              hipStream_t stream) {
    const float* x  = (const float*)d_in[0];   // [262144, 64]
    const float* cb = (const float*)d_in[1];   // [1024, 64]
    float* out = (float*)d_out;
    float* out_q    = out;                               // [N*D]
    float* out_loss = out + (size_t)N_ROWS * DIM;        // [2]
    float* out_idx  = out_loss + 2;                      // [N]

    char* ws = (char*)d_ws;
    float*          cnT     = (float*)(ws);                    // 262144 B
    float*          cc      = (float*)(ws + 262144);           //   4096 B
    unsigned short* frag    = (unsigned short*)(ws + 266240);  // 262144 B
    int*            cnt     = (int*)(ws + 528384);             //      4 B
    float*          dloss   = (float*)(ws + 528388);           //      4 B
    int*            list    = (int*)(ws + 528400);             // 262144 B
    float*          partial = (float*)(ws + 790544);           //   8192 B

    vq_prep   <<<KCODES / 4, 256, 0, stream>>>(cb, cnT, cc, frag, cnt, dloss);
    vq_mfma   <<<N_ROWS / 128, 256, 0, stream>>>(x, frag, cb, out_q, out_idx, cnt, list, partial);
    vq_recheck<<<512, 256, 0, stream>>>(x, cnT, cc, cb, cnt, list, out_idx, out_q, dloss);
    vq_final  <<<1, 256, 0, stream>>>(partial, dloss, out_loss);
}